// Round 11
// baseline (490.861 us; speedup 1.0000x reference)
//
#include <hip/hip_runtime.h>

// RecursiveNN, perfect binary tree, 8192 leaves, EMBED=512.
// LEVEL-MAJOR H: level h = dense [M_h][512] rows at roff(h) = 16384 - 2^(14-h).
// Children of (h,m) = (h-1,2m),(h-1,2m+1) -> level GEMM input is literally the
// previous level's buffer. Post-order id (final scatter only):
//   idx(h,m) = ((m+1)<<(h+1)) - 2 - popc(m).
// Numerics: fp16 hi+lo split H and W, 3-term MFMA (hh,hl,lh) => fp32-level.
// No intra-kernel grid sync (fence storms / RMW-spin / replay crash — closed).
// Round-11: dispatch-count 15 -> 11 via RECOMPUTE-FUSION of tail level pairs:
// one launch = producer blocks (level h, splitk16) + recomputer blocks that
// build level h+1 straight from level h-1 (stage 1: 32 rows x 512 recomputed
// into LDS on the idle MFMA pipe; stage 2: split-K tile from LDS). No block
// reads another block's same-launch output.

#define EMBED 512
#define K2    1024
#define WOFF  (EMBED * K2)
#define HSTR  520          // LDS row stride (halves): 16B-aligned, bank-staggered

typedef _Float16 half8 __attribute__((ext_vector_type(8)));
typedef float    floatx4 __attribute__((ext_vector_type(4)));

__device__ __forceinline__ float relu_f(float x) { return fmaxf(x, 0.0f); }

#define GLDS16(gp, lp)                                                        \
    __builtin_amdgcn_global_load_lds(                                         \
        (const __attribute__((address_space(1))) void*)(gp),                  \
        (__attribute__((address_space(3))) void*)(lp), 16, 0, 0)

#define MFMA16(a, b, c) __builtin_amdgcn_mfma_f32_16x16x32_f16(a, b, c, 0, 0, 0)

// ---------------------------------------------------------------------------
// pack W into fp16 hi/lo MFMA-B fragment order + leaves into level-0 rows.
__global__ __launch_bounds__(256)
void packleaf(const float* __restrict__ W, const float* __restrict__ emb,
              const int* __restrict__ word,
              _Float16* __restrict__ Whp,       // lo at +WOFF
              _Float16* __restrict__ Hh, _Float16* __restrict__ Hl,
              int nLeaves)
{
    int tid = threadIdx.x;
    int wave = tid >> 6, lane = tid & 63;

    {   // ---- pack W: 65536 jobs = 256 blocks x 256 threads
        int t = blockIdx.x * 256 + tid;
        int n = t >> 7, kc = t & 127;
        const float* src = W + (size_t)n * K2 + kc * 8;
        int s = kc >> 2, quad = kc & 3;
        int ln = (quad << 4) | (n & 15);
        size_t off = (size_t)(n >> 4) * 16384 + (size_t)s * 512 + (size_t)ln * 8;
        half8 hi, lo;
#pragma unroll
        for (int j = 0; j < 8; ++j) {
            float w = src[j];
            _Float16 h16 = (_Float16)w;
            hi[j] = h16;
            lo[j] = (_Float16)(w - (float)h16);
        }
        *(half8*)(Whp + off) = hi;
        *(half8*)(Whp + WOFF + off) = lo;
    }
    {   // ---- leaves -> level-0 rows (m-order, coalesced)
#pragma unroll
        for (int i = 0; i < 8; ++i) {
            int m = blockIdx.x * 32 + wave * 8 + i;
            if (m < nLeaves) {
                int wd = word[2 * m - __popc(m)];    // post-order leaf id
                const float4* src = (const float4*)(emb + (size_t)wd * EMBED) + lane * 2;
                float4 a = src[0], b = src[1];
                float v[8] = {a.x, a.y, a.z, a.w, b.x, b.y, b.z, b.w};
                half8 hi, lo;
#pragma unroll
                for (int j = 0; j < 8; ++j) {
                    float x = relu_f(v[j]);
                    _Float16 h16 = (_Float16)x;
                    hi[j] = h16;
                    lo[j] = (_Float16)(x - (float)h16);
                }
                *(half8*)(Hh + (size_t)m * EMBED + lane * 8) = hi;
                *(half8*)(Hl + (size_t)m * EMBED + lane * 8) = lo;
            }
        }
    }
}

// ---------------------------------------------------------------------------
// Level GEMM for h=1,2 (M multiple of 64). Block = 64x64, 4 waves:
// slice = wave>>1 (K-half = child), nh = wave&1 (col-half). A staged via
// global_load_lds into fragment-order slots; B direct from packed global.
__global__ __launch_bounds__(256)
void gemm_lvl(const _Float16* __restrict__ Ap,  // prev level hi (lo at +hoff)
              const _Float16* __restrict__ Wp,  // Whp (lo at +WOFF)
              const float* __restrict__ bW,
              _Float16* __restrict__ Cp,        // cur level hi (lo at +hoff)
              int hoff)
{
    __shared__ _Float16 As[16384];              // 32 KB: 32 fragment slots x 1 KB
    __shared__ float Red[4096];                 // 16 KB: 64x64 fp32

    int tid = threadIdx.x;
    int wave = tid >> 6, lane = tid & 63;
    int q = lane >> 4, r = lane & 15;
    int slice = wave >> 1, nh = wave & 1;
    int bm0 = blockIdx.x * 64, bn0 = blockIdx.y * 64;

    const _Float16* Asrc = Ap + (size_t)(nh ? hoff : 0)
                         + (size_t)(bm0 + r) * 1024 + slice * 512 + q * 8;

    floatx4 acc[4][2];
#pragma unroll
    for (int t = 0; t < 4; ++t)
#pragma unroll
        for (int u = 0; u < 2; ++u) acc[t][u] = (floatx4){0.f, 0.f, 0.f, 0.f};

    for (int kc = 0; kc < 8; ++kc) {
#pragma unroll
        for (int t = 0; t < 4; ++t)
#pragma unroll
            for (int s2 = 0; s2 < 2; ++s2) {
                const _Float16* gp = Asrc + t * (16 * 1024) + kc * 64 + s2 * 32;
                GLDS16(gp, &As[(slice * 16 + t * 4 + s2 * 2 + nh) * 512]);
            }
        __syncthreads();

#pragma unroll
        for (int s2 = 0; s2 < 2; ++s2) {
            half8 bh[2], bl[2];
#pragma unroll
            for (int u = 0; u < 2; ++u) {
                const _Float16* pb = Wp + (size_t)(blockIdx.y * 4 + nh * 2 + u) * 16384
                                   + (size_t)(slice * 16 + kc * 2 + s2) * 512 + lane * 8;
                bh[u] = *(const half8*)pb;
                bl[u] = *(const half8*)(pb + WOFF);
            }
#pragma unroll
            for (int t = 0; t < 4; ++t) {
                half8 ah = *(const half8*)&As[(slice * 16 + t * 4 + s2 * 2 + 0) * 512 + lane * 8];
                half8 al = *(const half8*)&As[(slice * 16 + t * 4 + s2 * 2 + 1) * 512 + lane * 8];
#pragma unroll
                for (int u = 0; u < 2; ++u) {
                    acc[t][u] = MFMA16(ah, bh[u], acc[t][u]);
                    acc[t][u] = MFMA16(ah, bl[u], acc[t][u]);
                    acc[t][u] = MFMA16(al, bh[u], acc[t][u]);
                }
            }
        }
        __syncthreads();
    }

    if (slice == 1) {
#pragma unroll
        for (int t = 0; t < 4; ++t)
#pragma unroll
            for (int u = 0; u < 2; ++u)
#pragma unroll
                for (int reg = 0; reg < 4; ++reg)
                    Red[(t * 16 + q * 4 + reg) * 64 + nh * 32 + u * 16 + r]
                        = acc[t][u][reg];
    }
    __syncthreads();
    if (slice == 0) {
#pragma unroll
        for (int t = 0; t < 4; ++t)
#pragma unroll
            for (int u = 0; u < 2; ++u) {
                int col = bn0 + nh * 32 + u * 16 + r;
                float bw = bW[col];
#pragma unroll
                for (int reg = 0; reg < 4; ++reg) {
                    int ml = t * 16 + q * 4 + reg;
                    float v = acc[t][u][reg]
                            + Red[ml * 64 + nh * 32 + u * 16 + r];
                    float x = relu_f(v + bw);
                    _Float16 hi = (_Float16)x;
                    size_t o = (size_t)(bm0 + ml) * EMBED + col;
                    Cp[o] = hi;
                    Cp[o + hoff] = (_Float16)(x - (float)hi);
                }
            }
    }
}

// ---------------------------------------------------------------------------
// 32x32 split-K kernel (h=3,4; M multiple of 32). grid = (M/32, 16).
__global__ __launch_bounds__(256)
void gemm_splitk32(const _Float16* __restrict__ Ap, const _Float16* __restrict__ Wp,
                   const float* __restrict__ bW,
                   _Float16* __restrict__ Cp, int hoff)
{
    __shared__ float red[4096];

    int tid = threadIdx.x;
    int wave = tid >> 6, lane = tid & 63;
    int q = lane >> 4, r = lane & 15;
    int m0 = blockIdx.x * 32, n0 = blockIdx.y * 32;

    const _Float16 *pAh[2], *pAl[2];
#pragma unroll
    for (int mi = 0; mi < 2; ++mi) {
        int m = m0 + mi * 16 + r;
        int prow = 2 * m + (wave >> 1);
        int kb = (wave & 1) * 256;
        pAh[mi] = Ap + (size_t)prow * EMBED + kb + q * 8;
        pAl[mi] = pAh[mi] + hoff;
    }
    const _Float16* pB[2];
#pragma unroll
    for (int u = 0; u < 2; ++u)
        pB[u] = Wp + (size_t)(blockIdx.y * 2 + u) * 16384
              + (size_t)(wave * 8) * 512 + lane * 8;

    floatx4 acc[2][2];
#pragma unroll
    for (int mi = 0; mi < 2; ++mi)
#pragma unroll
        for (int u = 0; u < 2; ++u) acc[mi][u] = (floatx4){0.f, 0.f, 0.f, 0.f};

#pragma unroll
    for (int s = 0; s < 8; ++s) {
        half8 ah[2], al[2], bh[2], bl[2];
#pragma unroll
        for (int mi = 0; mi < 2; ++mi) {
            ah[mi] = *(const half8*)(pAh[mi] + s * 32);
            al[mi] = *(const half8*)(pAl[mi] + s * 32);
        }
#pragma unroll
        for (int u = 0; u < 2; ++u) {
            bh[u] = *(const half8*)(pB[u] + s * 512);
            bl[u] = *(const half8*)(pB[u] + s * 512 + WOFF);
        }
#pragma unroll
        for (int mi = 0; mi < 2; ++mi)
#pragma unroll
            for (int u = 0; u < 2; ++u) {
                acc[mi][u] = MFMA16(ah[mi], bh[u], acc[mi][u]);
                acc[mi][u] = MFMA16(ah[mi], bl[u], acc[mi][u]);
                acc[mi][u] = MFMA16(al[mi], bh[u], acc[mi][u]);
            }
    }

#pragma unroll
    for (int mi = 0; mi < 2; ++mi)
#pragma unroll
        for (int u = 0; u < 2; ++u)
#pragma unroll
            for (int reg = 0; reg < 4; ++reg)
                red[wave * 1024 + (mi * 16 + q * 4 + reg) * 32 + u * 16 + r]
                    = acc[mi][u][reg];
    __syncthreads();

    int row = tid >> 3, c4 = (tid & 7) * 4;
    _Float16 hi4[4], lo4[4];
#pragma unroll
    for (int j = 0; j < 4; ++j) {
        int c = row * 32 + c4 + j;
        float v = red[c] + red[1024 + c] + red[2048 + c] + red[3072 + c];
        float x = relu_f(v + bW[n0 + c4 + j]);
        _Float16 hi = (_Float16)x;
        hi4[j] = hi;
        lo4[j] = (_Float16)(x - (float)hi);
    }
    size_t o = (size_t)(m0 + row) * EMBED + n0 + c4;
#pragma unroll
    for (int j = 0; j < 4; ++j) { Cp[o + j] = hi4[j]; Cp[o + hoff + j] = lo4[j]; }
}

// ---------------------------------------------------------------------------
// 16x16 split-K kernel (single level). grid = (ceil(M/16), 32).
__global__ __launch_bounds__(256)
void gemm_splitk(const _Float16* __restrict__ Ap, const _Float16* __restrict__ Wp,
                 const float* __restrict__ bW,
                 _Float16* __restrict__ Cp, int hoff, int M)
{
    __shared__ float red[1024];

    int tid = threadIdx.x;
    int wave = tid >> 6, lane = tid & 63;
    int q = lane >> 4, r = lane & 15;
    int mt = blockIdx.x, u = blockIdx.y;

    int m = mt * 16 + r;
    if (m >= M) m = M - 1;
    int prow = 2 * m + (wave >> 1);
    int kb = (wave & 1) * 256;
    const _Float16* pAh = Ap + (size_t)prow * EMBED + kb + q * 8;
    const _Float16* pAl = pAh + hoff;
    const _Float16* pB  = Wp + (size_t)u * 16384 + (size_t)(wave * 8) * 512 + lane * 8;

    floatx4 acc = (floatx4){0.f, 0.f, 0.f, 0.f};
#pragma unroll
    for (int s = 0; s < 8; ++s) {
        half8 ah = *(const half8*)(pAh + s * 32);
        half8 al = *(const half8*)(pAl + s * 32);
        half8 bh = *(const half8*)(pB + s * 512);
        half8 bl = *(const half8*)(pB + s * 512 + WOFF);
        acc = MFMA16(ah, bh, acc);
        acc = MFMA16(ah, bl, acc);
        acc = MFMA16(al, bh, acc);
    }
#pragma unroll
    for (int reg = 0; reg < 4; ++reg)
        red[wave * 256 + (q * 4 + reg) * 16 + r] = acc[reg];
    __syncthreads();

    int row = tid >> 4, col = tid & 15;
    float v = red[row * 16 + col] + red[256 + row * 16 + col]
            + red[512 + row * 16 + col] + red[768 + row * 16 + col];
    int mm = mt * 16 + row;
    if (mm < M) {
        int colg = u * 16 + col;
        float x = relu_f(v + bW[colg]);
        _Float16 hi = (_Float16)x;
        size_t o = (size_t)mm * EMBED + colg;
        Cp[o] = hi;
        Cp[o + hoff] = (_Float16)(x - (float)hi);
    }
}

// ---------------------------------------------------------------------------
// Fused pair (levels h, h+1) in ONE launch, no cross-block deps.
// Blocks bx < mtiles_h: producers — level-h split-K tile (as gemm_splitk),
//   input Pp (level h-1), output Ch.
// Blocks bx >= mtiles_h: recomputers — stage 1 recomputes their 32 level-h
//   rows (full 512 cols) from Pp into LDS; stage 2 = split-K tile for level
//   h+1 reading A from LDS, output Cn. Mh/Mn = level sizes (Mn = Mh/2).
__global__ __launch_bounds__(256)
void fused_pair(const _Float16* __restrict__ Pp,   // level h-1 hi (lo at +hoff)
                const _Float16* __restrict__ Wp,
                const float* __restrict__ bW,
                _Float16* __restrict__ Ch, _Float16* __restrict__ Cn,
                int hoff, int Mh, int Mn, int mtiles_h)
{
    __shared__ _Float16 Hs[2][32 * HSTR];       // ~66.5 KB recomputed level-h
    __shared__ float red[1024];

    int tid = threadIdx.x;
    int wave = tid >> 6, lane = tid & 63;
    int q = lane >> 4, r = lane & 15;
    int u = blockIdx.y;

    if ((int)blockIdx.x < mtiles_h) {
        // ================= producer: level-h 16x16 split-K tile ============
        int mt = blockIdx.x;
        int m = mt * 16 + r;
        if (m >= Mh) m = Mh - 1;
        int prow = 2 * m + (wave >> 1);
        int kb = (wave & 1) * 256;
        const _Float16* pAh = Pp + (size_t)prow * EMBED + kb + q * 8;
        const _Float16* pAl = pAh + hoff;
        const _Float16* pB  = Wp + (size_t)u * 16384 + (size_t)(wave * 8) * 512 + lane * 8;

        floatx4 acc = (floatx4){0.f, 0.f, 0.f, 0.f};
#pragma unroll
        for (int s = 0; s < 8; ++s) {
            half8 ah = *(const half8*)(pAh + s * 32);
            half8 al = *(const half8*)(pAl + s * 32);
            half8 bh = *(const half8*)(pB + s * 512);
            half8 bl = *(const half8*)(pB + s * 512 + WOFF);
            acc = MFMA16(ah, bh, acc);
            acc = MFMA16(ah, bl, acc);
            acc = MFMA16(al, bh, acc);
        }
#pragma unroll
        for (int reg = 0; reg < 4; ++reg)
            red[wave * 256 + (q * 4 + reg) * 16 + r] = acc[reg];
        __syncthreads();

        int row = tid >> 4, col = tid & 15;
        float v = red[row * 16 + col] + red[256 + row * 16 + col]
                + red[512 + row * 16 + col] + red[768 + row * 16 + col];
        int mm = mt * 16 + row;
        if (mm < Mh) {
            int colg = u * 16 + col;
            float x = relu_f(v + bW[colg]);
            _Float16 hi = (_Float16)x;
            size_t o = (size_t)mm * EMBED + colg;
            Ch[o] = hi;
            Ch[o + hoff] = (_Float16)(x - (float)hi);
        }
        return;
    }

    // ================= recomputer: level h+1 tile via LDS level-h ==========
    int mt2 = blockIdx.x - mtiles_h;

    {   // ---- stage 1: level-h rows 32*mt2 .. +31, all 512 cols -> LDS
        int a = wave >> 1, chh = wave & 1;      // m-tile, col-half
        int rowh = mt2 * 32 + a * 16 + r;
        if (rowh >= Mh) rowh = Mh - 1;

        floatx4 acc[16];
#pragma unroll
        for (int j = 0; j < 16; ++j) acc[j] = (floatx4){0.f, 0.f, 0.f, 0.f};

        for (int s = 0; s < 32; ++s) {          // full K=1024
            const _Float16* pa = Pp + (size_t)(2 * rowh + (s >> 4)) * EMBED
                               + (s & 15) * 32 + q * 8;
            half8 ah = *(const half8*)pa;
            half8 al = *(const half8*)(pa + hoff);
#pragma unroll
            for (int j = 0; j < 16; ++j) {
                const _Float16* pb = Wp + (size_t)(chh * 16 + j) * 16384
                                   + (size_t)s * 512 + lane * 8;
                half8 bh = *(const half8*)pb;
                half8 bl = *(const half8*)(pb + WOFF);
                acc[j] = MFMA16(ah, bh, acc[j]);
                acc[j] = MFMA16(ah, bl, acc[j]);
                acc[j] = MFMA16(al, bh, acc[j]);
            }
        }
#pragma unroll
        for (int j = 0; j < 16; ++j) {
            int col = (chh * 16 + j) * 16 + r;
            float bw = bW[col];
#pragma unroll
            for (int reg = 0; reg < 4; ++reg) {
                int lrow = a * 16 + q * 4 + reg;
                float x = relu_f(acc[j][reg] + bw);
                _Float16 hi = (_Float16)x;
                Hs[0][lrow * HSTR + col] = hi;
                Hs[1][lrow * HSTR + col] = (_Float16)(x - (float)hi);
            }
        }
    }
    __syncthreads();

    {   // ---- stage 2: level h+1 16x16 split-K tile, A from LDS
        int rl = r;
        if (rl >= Mn) rl = Mn - 1;
        int lrow = 2 * rl + (wave >> 1);        // LDS-local level-h row
        int kb = (wave & 1) * 256;
        const _Float16* pB = Wp + (size_t)u * 16384 + (size_t)(wave * 8) * 512 + lane * 8;

        floatx4 acc = (floatx4){0.f, 0.f, 0.f, 0.f};
#pragma unroll
        for (int s = 0; s < 8; ++s) {
            half8 ah = *(const half8*)&Hs[0][lrow * HSTR + kb + s * 32 + q * 8];
            half8 al = *(const half8*)&Hs[1][lrow * HSTR + kb + s * 32 + q * 8];
            half8 bh = *(const half8*)(pB + s * 512);
            half8 bl = *(const half8*)(pB + s * 512 + WOFF);
            acc = MFMA16(ah, bh, acc);
            acc = MFMA16(ah, bl, acc);
            acc = MFMA16(al, bh, acc);
        }
#pragma unroll
        for (int reg = 0; reg < 4; ++reg)
            red[wave * 256 + (q * 4 + reg) * 16 + r] = acc[reg];
        __syncthreads();

        int row = tid >> 4, col = tid & 15;
        float v = red[row * 16 + col] + red[256 + row * 16 + col]
                + red[512 + row * 16 + col] + red[768 + row * 16 + col];
        int mm = mt2 * 16 + row;
        if (mm < Mn) {
            int colg = u * 16 + col;
            float x = relu_f(v + bW[colg]);
            _Float16 hi = (_Float16)x;
            size_t o = (size_t)mm * EMBED + colg;
            Cn[o] = hi;
            Cn[o + hoff] = (_Float16)(x - (float)hi);
        }
    }
}

// ---------------------------------------------------------------------------
// Projection: level-major row j -> out[idx(h,m)].
__global__ __launch_bounds__(256)
void out_kernel(const _Float16* __restrict__ Hh, const _Float16* __restrict__ Hl,
                const float* __restrict__ P, const float* __restrict__ bP,
                float* __restrict__ out, int nNodes)
{
    int t = blockIdx.x * 256 + threadIdx.x;
    int j = t >> 6, lane = t & 63;
    if (j >= nNodes) return;
    int v = nNodes - j;
    int h = 13 - (31 - __clz(v));
    int m = j - ((nNodes + 1) - (1 << (13 - h + 1)));
    int node = ((m + 1) << (h + 1)) - 2 - __popc(m);

    half8 hv = *(const half8*)(Hh + (size_t)j * EMBED + lane * 8);
    half8 lv = *(const half8*)(Hl + (size_t)j * EMBED + lane * 8);
    float hx[8];
#pragma unroll
    for (int k = 0; k < 8; ++k) hx[k] = (float)hv[k] + (float)lv[k];
    float s[5];
#pragma unroll
    for (int c = 0; c < 5; ++c) {
        const float* p = P + c * EMBED + lane * 8;
        float4 p0 = *(const float4*)p;
        float4 p1 = *(const float4*)(p + 4);
        s[c] = hx[0] * p0.x + hx[1] * p0.y + hx[2] * p0.z + hx[3] * p0.w
             + hx[4] * p1.x + hx[5] * p1.y + hx[6] * p1.z + hx[7] * p1.w;
    }
#pragma unroll
    for (int o = 32; o > 0; o >>= 1)
#pragma unroll
        for (int c = 0; c < 5; ++c)
            s[c] += __shfl_down(s[c], o, 64);
    if (lane == 0) {
#pragma unroll
        for (int c = 0; c < 5; ++c)
            out[(size_t)node * 5 + c] = s[c] + bP[c];
    }
}

// ---------------------------------------------------------------------------
extern "C" void kernel_launch(void* const* d_in, const int* in_sizes, int n_in,
                              void* d_out, int out_size, void* d_ws, size_t ws_size,
                              hipStream_t stream)
{
    const int*   word = (const int*)d_in[1];
    const float* emb  = (const float*)d_in[4];
    const float* W    = (const float*)d_in[5];
    const float* bW   = (const float*)d_in[6];
    const float* P    = (const float*)d_in[7];
    const float* bP   = (const float*)d_in[8];
    float* out = (float*)d_out;

    int nNodes  = in_sizes[0];            // 16383
    int nLeaves = (nNodes + 1) / 2;       // 8192
    int nRows   = nNodes + 1;             // 16384

    int hoff = nRows * EMBED;             // halves between Hh and Hl
    _Float16* Hh  = (_Float16*)d_ws;
    _Float16* Hl  = Hh + hoff;
    _Float16* Whp = Hl + hoff;            // hi; lo at +WOFF

    auto roff = [&](int h) { return nRows - (1 << (14 - h)); };
    auto lvl  = [&](int h) { return Hh + (size_t)roff(h) * EMBED; };

    packleaf<<<dim3(256), dim3(256), 0, stream>>>(
        W, emb, word, Whp, Hh, Hl, nLeaves);

    for (int h = 1; h <= 2; ++h) {        // M = 4096, 2048
        int M = 1 << (13 - h);
        gemm_lvl<<<dim3(M / 64, 8), dim3(256), 0, stream>>>(
            lvl(h - 1), Whp, bW, lvl(h), hoff);
    }
    for (int h = 3; h <= 4; ++h) {        // M = 1024, 512
        int M = 1 << (13 - h);
        gemm_splitk32<<<dim3(M / 32, 16), dim3(256), 0, stream>>>(
            lvl(h - 1), Whp, bW, lvl(h), hoff);
    }
    // fused tail pairs: (5,6) (7,8) (9,10) (11,12)
    for (int h = 5; h <= 11; h += 2) {
        int Mh = 1 << (13 - h);
        int Mn = Mh >> 1;
        int mt_h = (Mh + 15) / 16;
        int mt_n = (Mn + 15) / 16;
        fused_pair<<<dim3(mt_h + mt_n, 32), dim3(256), 0, stream>>>(
            lvl(h - 1), Whp, bW, lvl(h), lvl(h + 1), hoff, Mh, Mn, mt_h);
    }
    // level 13 (root)
    gemm_splitk<<<dim3(1, 32), dim3(256), 0, stream>>>(
        lvl(12), Whp, bW, lvl(13), hoff, 1);

    out_kernel<<<dim3((nNodes * 64 + 255) / 256), dim3(256), 0, stream>>>(
        Hh, Hl, P, bP, out, nNodes);
}